// Round 9
// baseline (35.346 us; speedup 1.0000x reference)
//
#include <hip/hip_runtime.h>

#define IMG_H 512
#define IMG_W 512
#define MAX_STREAKS 64
#define ROWS_PER_BLOCK 8   // 8 rows * 512 cols = 4096 scalars = 1024 float4 per block

typedef float v4f __attribute__((ext_vector_type(4)));
typedef int   v4i __attribute__((ext_vector_type(4)));

__device__ __forceinline__ v4f blend4(v4f xv, v4f fv) {
    v4f o;
    o.x = fminf(fmaxf(fmaf(xv.x, fv.x, 1.0f - fv.x), 0.0f), 1.0f);
    o.y = fminf(fmaxf(fmaf(xv.y, fv.y, 1.0f - fv.y), 0.0f), 1.0f);
    o.z = fminf(fmaxf(fmaf(xv.z, fv.z, 1.0f - fv.z), 0.0f), 1.0f);
    o.w = fminf(fmaxf(fmaf(xv.w, fv.w, 1.0f - fv.w), 0.0f), 1.0f);
    return o;
}

// Fused rain streaks, async-staged:
//  1. issue this thread's 4 global x loads FIRST (HBM latency hides under prologue)
//  2. prologue: zero LDS count tile, rasterize overlap counts for the block's
//     8 rows (O(streaks) atomics) — 2 barriers total
//  3. each thread reads its OWN 4 count-slots, converts k -> f=(1-a)^k in
//     registers (no write-back, no third barrier), blends, plain store
//     (round-8 A/B: plain stores beat nt-stores — out rides L3).
__global__ void __launch_bounds__(256, 8)
rain_fused_kernel(const v4f* __restrict__ x,
                  const float* __restrict__ alpha,
                  const int* __restrict__ xc,
                  const int* __restrict__ y0,
                  const int* __restrict__ y1_off,
                  v4f* __restrict__ out,
                  int n_streaks) {
    __shared__ int s_xc[MAX_STREAKS], s_y0[MAX_STREAKS], s_y1[MAX_STREAKS];
    __shared__ int s_hist[ROWS_PER_BLOCK * IMG_W];      // 16 KB counts
    v4i* s_h4 = (v4i*)s_hist;                           // 1024 entries

    const int tid = threadIdx.x;

    // --- 1. issue global loads before any LDS traffic ---
    const v4f* xb = x + (size_t)blockIdx.x * 1024;
    v4f*       ob = out + (size_t)blockIdx.x * 1024;
    v4f x0 = xb[tid];
    v4f x1 = xb[256 + tid];
    v4f x2 = xb[512 + tid];
    v4f x3 = xb[768 + tid];

    // --- 2. prologue ---
    if (tid < n_streaks) {
        s_xc[tid] = xc[tid];
        s_y0[tid] = y0[tid];
        s_y1[tid] = y1_off[tid] + IMG_H / 2;
    }
    #pragma unroll
    for (int i = tid; i < ROWS_PER_BLOCK * IMG_W / 4; i += 256) {
        v4i z = {0, 0, 0, 0};
        s_h4[i] = z;
    }
    __syncthreads();

    const int hbase = (blockIdx.x & 63) * ROWS_PER_BLOCK;  // row-chunk

    // Rasterize: one (row, streak) pair per work item; each streak touches
    // at most 2 columns of a row.
    for (int p = tid; p < (n_streaks << 3); p += 256) {
        int r = p & 7, s = p >> 3;
        int h = hbase + r;
        if (h >= s_y0[s] && h < s_y1[s]) {
            int c = s_xc[s];
            atomicAdd(&s_hist[(r << 9) + (c - 1 > 0 ? c - 1 : 0)], 1);
            if (c >= 1) atomicAdd(&s_hist[(r << 9) + c], 1);
        }
    }
    __syncthreads();

    // --- 3. counts -> f in registers (thread-owned slots), blend, store ---
    const float l2f = __log2f(1.0f - alpha[0]);
    v4i k0 = s_h4[tid];
    v4i k1 = s_h4[256 + tid];
    v4i k2 = s_h4[512 + tid];
    v4i k3 = s_h4[768 + tid];

    v4f f0, f1, f2, f3;
    f0.x = exp2f(l2f * (float)k0.x); f0.y = exp2f(l2f * (float)k0.y);
    f0.z = exp2f(l2f * (float)k0.z); f0.w = exp2f(l2f * (float)k0.w);
    f1.x = exp2f(l2f * (float)k1.x); f1.y = exp2f(l2f * (float)k1.y);
    f1.z = exp2f(l2f * (float)k1.z); f1.w = exp2f(l2f * (float)k1.w);
    f2.x = exp2f(l2f * (float)k2.x); f2.y = exp2f(l2f * (float)k2.y);
    f2.z = exp2f(l2f * (float)k2.z); f2.w = exp2f(l2f * (float)k2.w);
    f3.x = exp2f(l2f * (float)k3.x); f3.y = exp2f(l2f * (float)k3.y);
    f3.z = exp2f(l2f * (float)k3.z); f3.w = exp2f(l2f * (float)k3.w);

    ob[tid]       = blend4(x0, f0);
    ob[256 + tid] = blend4(x1, f1);
    ob[512 + tid] = blend4(x2, f2);
    ob[768 + tid] = blend4(x3, f3);
}

extern "C" void kernel_launch(void* const* d_in, const int* in_sizes, int n_in,
                              void* d_out, int out_size, void* d_ws, size_t ws_size,
                              hipStream_t stream) {
    const float* x      = (const float*)d_in[0];
    const float* alpha  = (const float*)d_in[1];
    const int*   xc     = (const int*)d_in[2];
    const int*   y0     = (const int*)d_in[3];
    const int*   y1_off = (const int*)d_in[4];
    float* out = (float*)d_out;

    int n_streaks = in_sizes[2];

    // out_size = 32*3*512*512 = 25,165,824 scalars; 4096 per block -> 6144 blocks.
    int blocks = out_size / (ROWS_PER_BLOCK * IMG_W);
    rain_fused_kernel<<<blocks, 256, 0, stream>>>(
        (const v4f*)x, alpha, xc, y0, y1_off, (v4f*)out, n_streaks);
}